// Round 1
// baseline (342.748 us; speedup 1.0000x reference)
//
#include <hip/hip_runtime.h>
#include <hip/hip_bf16.h>
#include <cmath>

#define DEV __device__ __forceinline__

typedef float  f32x4  __attribute__((ext_vector_type(4)));
typedef __bf16 bf16x8 __attribute__((ext_vector_type(8)));
using u16 = unsigned short;

constexpr int CB   = 2;     // batch
constexpr int CLEN = 1024;  // seq len
constexpr int CDM  = 1024;  // d_model
constexpr int CDI  = 2048;  // d_inner
constexpr int CM   = CB * CLEN;  // 2048 GEMM rows
constexpr int NCHUNK = 16;  // scan chunks
constexpr int CHL    = 64;  // chunk length

DEV u16 f2bf(float f) {
  unsigned u = __builtin_bit_cast(unsigned, f);
  unsigned r = (u + 0x7fffu + ((u >> 16) & 1u)) >> 16;  // RNE
  return (u16)r;
}

// ------------------------------------------------------------------
// casts
// ------------------------------------------------------------------
__global__ void cast_bf16_k(const float* __restrict__ in, u16* __restrict__ out, int n4) {
  int i = blockIdx.x * blockDim.x + threadIdx.x;
  if (i >= n4) return;
  float4 v = reinterpret_cast<const float4*>(in)[i];
  ushort4 o;
  o.x = f2bf(v.x); o.y = f2bf(v.y); o.z = f2bf(v.z); o.w = f2bf(v.w);
  reinterpret_cast<ushort4*>(out)[i] = o;
}

// W_x (96 x 2048) -> bf16 padded to (128 x 2048), rows 96..127 = 0
__global__ void cast_pad_wx_k(const float* __restrict__ in, u16* __restrict__ out) {
  int i = blockIdx.x * blockDim.x + threadIdx.x;  // over 128*2048/4
  int base = i * 4;
  int row = base >> 11;
  int col = base & 2047;
  float4 v = make_float4(0.f, 0.f, 0.f, 0.f);
  if (row < 96) v = *reinterpret_cast<const float4*>(in + row * 2048 + col);
  ushort4 o;
  o.x = f2bf(v.x); o.y = f2bf(v.y); o.z = f2bf(v.z); o.w = f2bf(v.w);
  reinterpret_cast<ushort4*>(out)[i] = o;
}

// ------------------------------------------------------------------
// bf16 MFMA GEMM, NT layout: C[M][N] = A[M][K] * B[N][K]^T
// 128x128 tile, BK=32, 4 waves each computing 64x64 (4x4 MFMA tiles)
// EPI: 0 = plain fp32 store; 1 = fp32 + bf16 store; 2 = softplus(acc+bias[col])
// ------------------------------------------------------------------
DEV void gload_lds16(const void* g, void* l) {
  __builtin_amdgcn_global_load_lds(
      (const __attribute__((address_space(1))) void*)g,
      (__attribute__((address_space(3))) void*)l, 16, 0, 0);
}

template <int EPI>
__global__ __launch_bounds__(256, 2)
void gemm_bt(const u16* __restrict__ A, const u16* __restrict__ Bw,
             float* __restrict__ C, u16* __restrict__ Cb,
             const float* __restrict__ bias,
             int Nd, int Kd, int lda, int ldb, int ldc)
{
  __shared__ u16 As[128 * 32];
  __shared__ u16 Bs[128 * 32];
  const int tid  = threadIdx.x;
  const int wave = tid >> 6;
  const int lane = tid & 63;
  const int wm = wave >> 1, wn = wave & 1;
  const int row0 = blockIdx.y * 128;
  const int col0 = blockIdx.x * 128;
  const int lr = lane >> 2;        // row within a 16-row staging chunk
  const int lc = (lane & 3) * 8;   // 8 bf16 = 16B per lane

  f32x4 acc[4][4] = {};

  for (int k0 = 0; k0 < Kd; k0 += 32) {
#pragma unroll
    for (int j = 0; j < 2; ++j) {
      const int rb = j * 64 + wave * 16;   // 16 rows per issue per wave
      gload_lds16(A  + (size_t)(row0 + rb + lr) * lda + k0 + lc, As + rb * 32);
      gload_lds16(Bw + (size_t)(col0 + rb + lr) * ldb + k0 + lc, Bs + rb * 32);
    }
    __syncthreads();   // drains vmcnt for global_load_lds

    const int q  = lane >> 4;
    const int mr = lane & 15;
    bf16x8 af[4], bfr[4];
#pragma unroll
    for (int t = 0; t < 4; ++t) {
      af[t]  = *reinterpret_cast<const bf16x8*>(As + (wm * 64 + t * 16 + mr) * 32 + q * 8);
      bfr[t] = *reinterpret_cast<const bf16x8*>(Bs + (wn * 64 + t * 16 + mr) * 32 + q * 8);
    }
#pragma unroll
    for (int mt = 0; mt < 4; ++mt)
#pragma unroll
      for (int nt = 0; nt < 4; ++nt)
        acc[mt][nt] = __builtin_amdgcn_mfma_f32_16x16x32_bf16(af[mt], bfr[nt], acc[mt][nt], 0, 0, 0);
    __syncthreads();
  }

  const int q  = lane >> 4;
  const int cn = lane & 15;
#pragma unroll
  for (int mt = 0; mt < 4; ++mt)
#pragma unroll
    for (int nt = 0; nt < 4; ++nt)
#pragma unroll
      for (int r = 0; r < 4; ++r) {
        const int row = row0 + wm * 64 + mt * 16 + q * 4 + r;
        const int col = col0 + wn * 64 + nt * 16 + cn;
        float v = acc[mt][nt][r];
        if (EPI == 2) {
          v += bias[col];
          v = (v > 15.f) ? v : log1pf(__expf(v));   // softplus
        }
        C[(size_t)row * ldc + col] = v;
        if (EPI == 1) Cb[(size_t)row * ldc + col] = f2bf(v);
      }
}

// ------------------------------------------------------------------
// causal depthwise conv (k=4) + SiLU; writes fp32 and bf16 copies
// ------------------------------------------------------------------
__global__ void conv_silu_k(const float* __restrict__ xz, const float4* __restrict__ cw4,
                            const float* __restrict__ cb,
                            float* __restrict__ xc, u16* __restrict__ xcb)
{
  int idx = blockIdx.x * blockDim.x + threadIdx.x;  // over CB*CLEN*CDI
  int d   = idx & (CDI - 1);
  int row = idx >> 11;            // b*L + l
  int l   = row & (CLEN - 1);
  float4 wv = cw4[d];
  const float* wp = (const float*)&wv;
  float acc = cb[d];
#pragma unroll
  for (int i = 0; i < 4; ++i) {
    int ls = l - 3 + i;
    float v = (ls >= 0) ? xz[(size_t)(row - l + ls) * 4096 + d] : 0.f;
    acc += v * wp[i];
  }
  float s = acc / (1.f + __expf(-acc));   // silu
  xc[idx]  = s;
  xcb[idx] = f2bf(s);
}

// ------------------------------------------------------------------
// chunked selective scan: h_l = exp(dl*A)*h_{l-1} + dl*u*B_l
// phase1: per (b,d,chunk) compute P = prod(a), S = local scan (h_in=0)
// phase2: per (b,d,n) serial compose over 16 chunks -> h_in per chunk
// phase3: recompute with h_in, y = sum_n h*C + u*D, gate with silu(res)
// P/S/Hin layout: [b][chunk][n][d]  (coalesced over d)
// ------------------------------------------------------------------
__global__ __launch_bounds__(256)
void scan_p1(const float* __restrict__ delta, const float* __restrict__ xc,
             const float* __restrict__ xdbl, const float* __restrict__ A_log,
             float* __restrict__ P, float* __restrict__ S)
{
  __shared__ float sB[CHL * 16];
  const int t = threadIdx.x;
  const int d = blockIdx.x * 256 + t;
  const int c = blockIdx.y, b = blockIdx.z;

  for (int i = t; i < CHL * 16; i += 256) {
    int ll = i >> 4, n = i & 15;
    sB[i] = xdbl[(size_t)(b * CLEN + c * CHL + ll) * 128 + 64 + n];
  }
  __syncthreads();

  float An[16], Pv[16], Sv[16];
#pragma unroll
  for (int n = 0; n < 16; ++n) {
    An[n] = -__expf(A_log[d * 16 + n]);
    Pv[n] = 1.f; Sv[n] = 0.f;
  }
  const size_t rbase = (size_t)(b * CLEN + c * CHL) * CDI + d;
  for (int ll = 0; ll < CHL; ++ll) {
    float dl = delta[rbase + (size_t)ll * CDI];
    float u  = xc[rbase + (size_t)ll * CDI];
    float du = dl * u;
#pragma unroll
    for (int n = 0; n < 16; ++n) {
      float a = __expf(dl * An[n]);
      Pv[n] *= a;
      Sv[n] = a * Sv[n] + du * sB[ll * 16 + n];
    }
  }
  const size_t o = (size_t)((b * NCHUNK + c) * 16) * CDI + d;
#pragma unroll
  for (int n = 0; n < 16; ++n) {
    P[o + (size_t)n * CDI] = Pv[n];
    S[o + (size_t)n * CDI] = Sv[n];
  }
}

__global__ void scan_p2(const float* __restrict__ P, const float* __restrict__ S,
                        float* __restrict__ Hin)
{
  const int t = threadIdx.x;
  const int d = blockIdx.x * 256 + t;
  const int n = blockIdx.y, b = blockIdx.z;
  float h = 0.f;
  for (int c = 0; c < NCHUNK; ++c) {
    size_t o = (size_t)((b * NCHUNK + c) * 16 + n) * CDI + d;
    Hin[o] = h;
    h = P[o] * h + S[o];
  }
}

__global__ __launch_bounds__(256)
void scan_p3(const float* __restrict__ delta, const float* __restrict__ xc,
             const float* __restrict__ xdbl, const float* __restrict__ A_log,
             const float* __restrict__ Dvec, const float* __restrict__ xzres,
             const float* __restrict__ Hin, u16* __restrict__ ybarb)
{
  __shared__ float sB[CHL * 16];
  __shared__ float sC[CHL * 16];
  const int t = threadIdx.x;
  const int d = blockIdx.x * 256 + t;
  const int c = blockIdx.y, b = blockIdx.z;

  for (int i = t; i < CHL * 16; i += 256) {
    int ll = i >> 4, n = i & 15;
    size_t ro = (size_t)(b * CLEN + c * CHL + ll) * 128;
    sB[i] = xdbl[ro + 64 + n];
    sC[i] = xdbl[ro + 80 + n];
  }
  __syncthreads();

  float An[16], h[16];
  const size_t ho = (size_t)((b * NCHUNK + c) * 16) * CDI + d;
#pragma unroll
  for (int n = 0; n < 16; ++n) {
    An[n] = -__expf(A_log[d * 16 + n]);
    h[n]  = Hin[ho + (size_t)n * CDI];
  }
  const float Dd = Dvec[d];
  const size_t rbase = (size_t)(b * CLEN + c * CHL);
  for (int ll = 0; ll < CHL; ++ll) {
    float dl = delta[(rbase + ll) * CDI + d];
    float u  = xc[(rbase + ll) * CDI + d];
    float du = dl * u;
    float rs = xzres[(rbase + ll) * 4096 + CDI + d];
    float y  = 0.f;
#pragma unroll
    for (int n = 0; n < 16; ++n) {
      float a = __expf(dl * An[n]);
      h[n] = a * h[n] + du * sB[ll * 16 + n];
      y += h[n] * sC[ll * 16 + n];
    }
    y += u * Dd;
    float sr = rs / (1.f + __expf(-rs));   // silu(res)
    ybarb[(rbase + ll) * CDI + d] = f2bf(y * sr);
  }
}

// ------------------------------------------------------------------
extern "C" void kernel_launch(void* const* d_in, const int* in_sizes, int n_in,
                              void* d_out, int out_size, void* d_ws, size_t ws_size,
                              hipStream_t stream)
{
  (void)in_sizes; (void)n_in; (void)out_size; (void)ws_size;
  const float* x      = (const float*)d_in[0];
  const float* W_in   = (const float*)d_in[1];
  const float* conv_w = (const float*)d_in[2];
  const float* conv_b = (const float*)d_in[3];
  const float* W_x    = (const float*)d_in[4];
  const float* W_dt   = (const float*)d_in[5];
  const float* b_dt   = (const float*)d_in[6];
  const float* A_log  = (const float*)d_in[7];
  const float* Dvec   = (const float*)d_in[8];
  const float* W_out  = (const float*)d_in[9];
  float* out = (float*)d_out;

  char* w = (char*)d_ws;
  size_t off = 0;
  auto alloc = [&](size_t bytes) {
    void* p = w + off;
    off += (bytes + 255) & ~(size_t)255;
    return p;
  };
  u16*   xb     = (u16*)  alloc((size_t)CM * CDM * 2);          // x bf16
  u16*   W_inb  = (u16*)  alloc((size_t)4096 * 1024 * 2);
  float* xzres  = (float*)alloc((size_t)CM * 4096 * 4);         // in_proj out
  float* xc     = (float*)alloc((size_t)CM * CDI * 4);          // conv+silu fp32
  u16*   xcb    = (u16*)  alloc((size_t)CM * CDI * 2);
  u16*   W_xb   = (u16*)  alloc((size_t)128 * 2048 * 2);        // padded
  float* xdbl   = (float*)alloc((size_t)CM * 128 * 4);          // x_proj out (padded N=128)
  u16*   xdblb  = (u16*)  alloc((size_t)CM * 128 * 2);
  u16*   W_dtb  = (u16*)  alloc((size_t)2048 * 64 * 2);
  float* delta  = (float*)alloc((size_t)CM * CDI * 4);
  float* Pb     = (float*)alloc((size_t)CB * NCHUNK * 16 * CDI * 4);
  float* Sb     = (float*)alloc((size_t)CB * NCHUNK * 16 * CDI * 4);
  float* Hin    = (float*)alloc((size_t)CB * NCHUNK * 16 * CDI * 4);
  u16*   ybarb  = (u16*)  alloc((size_t)CM * CDI * 2);
  u16*   W_outb = (u16*)  alloc((size_t)1024 * 2048 * 2);

  dim3 blk(256);
  // casts
  cast_bf16_k<<<2097152 / 1024, blk, 0, stream>>>(x,     xb,     2097152 / 4);
  cast_bf16_k<<<4194304 / 1024, blk, 0, stream>>>(W_in,  W_inb,  4194304 / 4);
  cast_bf16_k<<< 131072 / 1024, blk, 0, stream>>>(W_dt,  W_dtb,   131072 / 4);
  cast_bf16_k<<<2097152 / 1024, blk, 0, stream>>>(W_out, W_outb, 2097152 / 4);
  cast_pad_wx_k<<<262144 / 1024, blk, 0, stream>>>(W_x, W_xb);

  // 1) in_proj: xzres[2048][4096] = xb[2048][1024] @ W_in[4096][1024]^T
  gemm_bt<0><<<dim3(32, 16), blk, 0, stream>>>(xb, W_inb, xzres, nullptr, nullptr,
                                               4096, 1024, 1024, 1024, 4096);
  // 2) conv + silu on xz half
  conv_silu_k<<<(CB * CLEN * CDI) / 256, blk, 0, stream>>>(xzres, (const float4*)conv_w,
                                                           conv_b, xc, xcb);
  // 3) x_proj: xdbl[2048][128] = xcb @ W_xb^T  (fp32 + bf16 out)
  gemm_bt<1><<<dim3(1, 16), blk, 0, stream>>>(xcb, W_xb, xdbl, xdblb, nullptr,
                                              128, 2048, 2048, 2048, 128);
  // 4) dt_proj + softplus: delta[2048][2048] = softplus(dlt @ W_dt^T + b_dt)
  gemm_bt<2><<<dim3(16, 16), blk, 0, stream>>>(xdblb, W_dtb, delta, nullptr, b_dt,
                                               2048, 64, 128, 64, 2048);
  // 5) selective scan (3-phase chunked)
  scan_p1<<<dim3(8, 16, 2), blk, 0, stream>>>(delta, xc, xdbl, A_log, Pb, Sb);
  scan_p2<<<dim3(8, 16, 2), blk, 0, stream>>>(Pb, Sb, Hin);
  scan_p3<<<dim3(8, 16, 2), blk, 0, stream>>>(delta, xc, xdbl, A_log, Dvec, xzres,
                                              Hin, ybarb);
  // 6) out_proj: out[2048][1024] = ybarb @ W_out^T
  gemm_bt<0><<<dim3(8, 16), blk, 0, stream>>>(ybarb, W_outb, out, nullptr, nullptr,
                                              1024, 2048, 2048, 2048, 1024);
}

// Round 2
// 260.294 us; speedup vs baseline: 1.3168x; 1.3168x over previous
//
#include <hip/hip_runtime.h>
#include <hip/hip_bf16.h>
#include <cmath>

#define DEV __device__ __forceinline__

typedef float  f32x4  __attribute__((ext_vector_type(4)));
typedef __bf16 bf16x8 __attribute__((ext_vector_type(8)));
using u16 = unsigned short;

constexpr int CB   = 2;     // batch
constexpr int CLEN = 1024;  // seq len
constexpr int CDM  = 1024;  // d_model
constexpr int CDI  = 2048;  // d_inner
constexpr int CM   = CB * CLEN;  // 2048 GEMM rows
constexpr int NCHUNK = 64;  // scan chunks (more chunks = more parallelism)
constexpr int CHL    = 16;  // chunk length

DEV u16 f2bf(float f) {
  unsigned u = __builtin_bit_cast(unsigned, f);
  unsigned r = (u + 0x7fffu + ((u >> 16) & 1u)) >> 16;  // RNE
  return (u16)r;
}

DEV ushort4 f4bf(float4 v) {
  ushort4 o;
  o.x = f2bf(v.x); o.y = f2bf(v.y); o.z = f2bf(v.z); o.w = f2bf(v.w);
  return o;
}

// ------------------------------------------------------------------
// one fused cast kernel: x, W_in, W_dt, W_out (plain) + W_x (pad 96->128 rows)
// index space is float4 groups, region boundaries precomputed
// ------------------------------------------------------------------
constexpr int CG_X   = 524288;                 // 2048*1024/4
constexpr int CG_WIN = CG_X   + 1048576;       // 4096*1024/4
constexpr int CG_WDT = CG_WIN + 32768;         // 2048*64/4
constexpr int CG_WO  = CG_WDT + 524288;        // 1024*2048/4
constexpr int CG_WX  = CG_WO  + 65536;         // 128*2048/4 (padded out)

__global__ void cast_all_k(const float* __restrict__ x, const float* __restrict__ W_in,
                           const float* __restrict__ W_dt, const float* __restrict__ W_out,
                           const float* __restrict__ W_x,
                           u16* __restrict__ xb, u16* __restrict__ W_inb,
                           u16* __restrict__ W_dtb, u16* __restrict__ W_outb,
                           u16* __restrict__ W_xb)
{
  int i = blockIdx.x * blockDim.x + threadIdx.x;
  if (i < CG_X) {
    reinterpret_cast<ushort4*>(xb)[i] = f4bf(reinterpret_cast<const float4*>(x)[i]);
  } else if (i < CG_WIN) {
    int j = i - CG_X;
    reinterpret_cast<ushort4*>(W_inb)[j] = f4bf(reinterpret_cast<const float4*>(W_in)[j]);
  } else if (i < CG_WDT) {
    int j = i - CG_WIN;
    reinterpret_cast<ushort4*>(W_dtb)[j] = f4bf(reinterpret_cast<const float4*>(W_dt)[j]);
  } else if (i < CG_WO) {
    int j = i - CG_WDT;
    reinterpret_cast<ushort4*>(W_outb)[j] = f4bf(reinterpret_cast<const float4*>(W_out)[j]);
  } else {
    int j = i - CG_WO;
    int base = j * 4, row = base >> 11, col = base & 2047;
    float4 v = make_float4(0.f, 0.f, 0.f, 0.f);
    if (row < 96) v = *reinterpret_cast<const float4*>(W_x + row * 2048 + col);
    reinterpret_cast<ushort4*>(W_xb)[j] = f4bf(v);
  }
}

// ------------------------------------------------------------------
// bf16 MFMA GEMM, NT layout: C[M][N] = A[M][K] * B[N][K]^T
// 128x128 tile, BK=32, 4 waves each computing 64x64 (4x4 MFMA tiles)
// EPI: 0 = plain fp32 store; 2 = softplus(acc+bias[col])
// SPLITK>1: blockIdx.z picks a K-slice, partial fp32 to C + z*slice_stride
// ------------------------------------------------------------------
DEV void gload_lds16(const void* g, void* l) {
  __builtin_amdgcn_global_load_lds(
      (const __attribute__((address_space(1))) void*)g,
      (__attribute__((address_space(3))) void*)l, 16, 0, 0);
}

template <int EPI, int SPLITK>
__global__ __launch_bounds__(256, 2)
void gemm_bt(const u16* __restrict__ A, const u16* __restrict__ Bw,
             float* __restrict__ C, const float* __restrict__ bias,
             int Nd, int Kd, int lda, int ldb, int ldc, size_t slice_stride)
{
  __shared__ u16 As[128 * 32];
  __shared__ u16 Bs[128 * 32];
  const int tid  = threadIdx.x;
  const int wave = tid >> 6;
  const int lane = tid & 63;
  const int wm = wave >> 1, wn = wave & 1;
  const int row0 = blockIdx.y * 128;
  const int col0 = blockIdx.x * 128;
  const int lr = lane >> 2;        // row within a 16-row staging chunk
  const int lc = (lane & 3) * 8;   // 8 bf16 = 16B per lane

  const int kper = Kd / SPLITK;
  const int kbeg = (SPLITK > 1) ? blockIdx.z * kper : 0;
  float* Cz = (SPLITK > 1) ? C + (size_t)blockIdx.z * slice_stride : C;

  f32x4 acc[4][4] = {};

  for (int k0 = kbeg; k0 < kbeg + kper; k0 += 32) {
#pragma unroll
    for (int j = 0; j < 2; ++j) {
      const int rb = j * 64 + wave * 16;   // 16 rows per issue per wave
      gload_lds16(A  + (size_t)(row0 + rb + lr) * lda + k0 + lc, As + rb * 32);
      gload_lds16(Bw + (size_t)(col0 + rb + lr) * ldb + k0 + lc, Bs + rb * 32);
    }
    __syncthreads();   // drains vmcnt for global_load_lds

    const int q  = lane >> 4;
    const int mr = lane & 15;
    bf16x8 af[4], bfr[4];
#pragma unroll
    for (int t = 0; t < 4; ++t) {
      af[t]  = *reinterpret_cast<const bf16x8*>(As + (wm * 64 + t * 16 + mr) * 32 + q * 8);
      bfr[t] = *reinterpret_cast<const bf16x8*>(Bs + (wn * 64 + t * 16 + mr) * 32 + q * 8);
    }
#pragma unroll
    for (int mt = 0; mt < 4; ++mt)
#pragma unroll
      for (int nt = 0; nt < 4; ++nt)
        acc[mt][nt] = __builtin_amdgcn_mfma_f32_16x16x32_bf16(af[mt], bfr[nt], acc[mt][nt], 0, 0, 0);
    __syncthreads();
  }

  const int q  = lane >> 4;
  const int cn = lane & 15;
#pragma unroll
  for (int mt = 0; mt < 4; ++mt)
#pragma unroll
    for (int nt = 0; nt < 4; ++nt)
#pragma unroll
      for (int r = 0; r < 4; ++r) {
        const int row = row0 + wm * 64 + mt * 16 + q * 4 + r;
        const int col = col0 + wn * 64 + nt * 16 + cn;
        float v = acc[mt][nt][r];
        if (EPI == 2) {
          v += bias[col];
          v = (v > 15.f) ? v : log1pf(__expf(v));   // softplus
        }
        Cz[(size_t)row * ldc + col] = v;
      }
}

// reduce 8 split-K partials of x_proj -> fp32 xdbl + bf16 xdblb
__global__ void xdbl_reduce_k(const float* __restrict__ part,
                              float* __restrict__ xdbl, u16* __restrict__ xdblb)
{
  int i = blockIdx.x * blockDim.x + threadIdx.x;   // over 2048*128/4 groups
  float4 s = reinterpret_cast<const float4*>(part)[i];
#pragma unroll
  for (int z = 1; z < 8; ++z) {
    float4 p = reinterpret_cast<const float4*>(part + (size_t)z * CM * 128)[i];
    s.x += p.x; s.y += p.y; s.z += p.z; s.w += p.w;
  }
  reinterpret_cast<float4*>(xdbl)[i] = s;
  reinterpret_cast<ushort4*>(xdblb)[i] = f4bf(s);
}

// ------------------------------------------------------------------
// causal depthwise conv (k=4) + SiLU; writes fp32 and bf16 copies
// ------------------------------------------------------------------
__global__ void conv_silu_k(const float* __restrict__ xz, const float4* __restrict__ cw4,
                            const float* __restrict__ cb,
                            float* __restrict__ xc, u16* __restrict__ xcb)
{
  int idx = blockIdx.x * blockDim.x + threadIdx.x;  // over CB*CLEN*CDI
  int d   = idx & (CDI - 1);
  int row = idx >> 11;            // b*L + l
  int l   = row & (CLEN - 1);
  float4 wv = cw4[d];
  const float* wp = (const float*)&wv;
  float acc = cb[d];
#pragma unroll
  for (int i = 0; i < 4; ++i) {
    int ls = l - 3 + i;
    float v = (ls >= 0) ? xz[(size_t)(row - l + ls) * 4096 + d] : 0.f;
    acc += v * wp[i];
  }
  float s = acc / (1.f + __expf(-acc));   // silu
  xc[idx]  = s;
  xcb[idx] = f2bf(s);
}

// ------------------------------------------------------------------
// chunked selective scan: h_l = exp(dl*A)*h_{l-1} + dl*u*B_l
// phase1: per (b,d,chunk) compute P = prod(a), S = local scan (h_in=0)
// phase2: per (b,d,n) serial compose over NCHUNK chunks -> h_in per chunk
// phase3: recompute with h_in, y = sum_n h*C + u*D, gate with silu(res)
// P/S/Hin layout: [b][chunk][n][d]  (coalesced over d)
// ------------------------------------------------------------------
__global__ __launch_bounds__(256)
void scan_p1(const float* __restrict__ delta, const float* __restrict__ xc,
             const float* __restrict__ xdbl, const float* __restrict__ A_log,
             float* __restrict__ P, float* __restrict__ S)
{
  __shared__ float sB[CHL * 16];
  const int t = threadIdx.x;
  const int d = blockIdx.x * 256 + t;
  const int c = blockIdx.y, b = blockIdx.z;

  if (t < CHL * 16) {
    int ll = t >> 4, n = t & 15;
    sB[t] = xdbl[(size_t)(b * CLEN + c * CHL + ll) * 128 + 64 + n];
  }
  __syncthreads();

  float An[16], Pv[16], Sv[16];
#pragma unroll
  for (int n = 0; n < 16; ++n) {
    An[n] = -__expf(A_log[d * 16 + n]);
    Pv[n] = 1.f; Sv[n] = 0.f;
  }
  const size_t rbase = (size_t)(b * CLEN + c * CHL) * CDI + d;
  for (int ll = 0; ll < CHL; ++ll) {
    float dl = delta[rbase + (size_t)ll * CDI];
    float u  = xc[rbase + (size_t)ll * CDI];
    float du = dl * u;
#pragma unroll
    for (int n = 0; n < 16; ++n) {
      float a = __expf(dl * An[n]);
      Pv[n] *= a;
      Sv[n] = a * Sv[n] + du * sB[ll * 16 + n];
    }
  }
  const size_t o = (size_t)((b * NCHUNK + c) * 16) * CDI + d;
#pragma unroll
  for (int n = 0; n < 16; ++n) {
    P[o + (size_t)n * CDI] = Pv[n];
    S[o + (size_t)n * CDI] = Sv[n];
  }
}

__global__ void scan_p2(const float* __restrict__ P, const float* __restrict__ S,
                        float* __restrict__ Hin)
{
  const int t = threadIdx.x;
  const int d = blockIdx.x * 256 + t;
  const int n = blockIdx.y, b = blockIdx.z;
  float h = 0.f;
#pragma unroll 8
  for (int c = 0; c < NCHUNK; ++c) {
    size_t o = (size_t)((b * NCHUNK + c) * 16 + n) * CDI + d;
    Hin[o] = h;
    h = P[o] * h + S[o];
  }
}

__global__ __launch_bounds__(256)
void scan_p3(const float* __restrict__ delta, const float* __restrict__ xc,
             const float* __restrict__ xdbl, const float* __restrict__ A_log,
             const float* __restrict__ Dvec, const float* __restrict__ xzres,
             const float* __restrict__ Hin, u16* __restrict__ ybarb)
{
  __shared__ float sB[CHL * 16];
  __shared__ float sC[CHL * 16];
  const int t = threadIdx.x;
  const int d = blockIdx.x * 256 + t;
  const int c = blockIdx.y, b = blockIdx.z;

  if (t < CHL * 16) {
    int ll = t >> 4, n = t & 15;
    size_t ro = (size_t)(b * CLEN + c * CHL + ll) * 128;
    sB[t] = xdbl[ro + 64 + n];
    sC[t] = xdbl[ro + 80 + n];
  }
  __syncthreads();

  float An[16], h[16];
  const size_t ho = (size_t)((b * NCHUNK + c) * 16) * CDI + d;
#pragma unroll
  for (int n = 0; n < 16; ++n) {
    An[n] = -__expf(A_log[d * 16 + n]);
    h[n]  = Hin[ho + (size_t)n * CDI];
  }
  const float Dd = Dvec[d];
  const size_t rbase = (size_t)(b * CLEN + c * CHL);
  for (int ll = 0; ll < CHL; ++ll) {
    float dl = delta[(rbase + ll) * CDI + d];
    float u  = xc[(rbase + ll) * CDI + d];
    float du = dl * u;
    float rs = xzres[(rbase + ll) * 4096 + CDI + d];
    float y  = 0.f;
#pragma unroll
    for (int n = 0; n < 16; ++n) {
      float a = __expf(dl * An[n]);
      h[n] = a * h[n] + du * sB[ll * 16 + n];
      y += h[n] * sC[ll * 16 + n];
    }
    y += u * Dd;
    float sr = rs / (1.f + __expf(-rs));   // silu(res)
    ybarb[(rbase + ll) * CDI + d] = f2bf(y * sr);
  }
}

// ------------------------------------------------------------------
extern "C" void kernel_launch(void* const* d_in, const int* in_sizes, int n_in,
                              void* d_out, int out_size, void* d_ws, size_t ws_size,
                              hipStream_t stream)
{
  (void)in_sizes; (void)n_in; (void)out_size; (void)ws_size;
  const float* x      = (const float*)d_in[0];
  const float* W_in   = (const float*)d_in[1];
  const float* conv_w = (const float*)d_in[2];
  const float* conv_b = (const float*)d_in[3];
  const float* W_x    = (const float*)d_in[4];
  const float* W_dt   = (const float*)d_in[5];
  const float* b_dt   = (const float*)d_in[6];
  const float* A_log  = (const float*)d_in[7];
  const float* Dvec   = (const float*)d_in[8];
  const float* W_out  = (const float*)d_in[9];
  float* out = (float*)d_out;

  // -------- workspace layout (manual, with lifetime-based aliasing) --------
  // Region A [0, 21.25M): xb/W_inb/xcb/W_xb/xdblb/W_dtb — all dead before p1.
  //   Pb (16M) aliases region A from offset 0.
  // Region B [21.25M, 37.25M): xpart (8M, dead after reduce), Sb (16M, dead
  //   after p2), ybarb (8M, written in p3) — sequential lifetimes.
  // Then non-aliased persistent buffers. Total = 122.25 MB.
  constexpr size_t MB = 1048576;
  char* w = (char*)d_ws;
  u16*   xb     = (u16*)(w + 0);                    // 4M
  u16*   W_inb  = (u16*)(w + 4 * MB);               // 8M
  u16*   xcb    = (u16*)(w + 12 * MB);              // 8M
  u16*   W_xb   = (u16*)(w + 20 * MB);              // 0.5M
  u16*   xdblb  = (u16*)(w + 20 * MB + 512 * 1024); // 0.5M
  u16*   W_dtb  = (u16*)(w + 21 * MB);              // 0.25M
  float* Pb     = (float*)(w + 0);                  // 16M (alias A)
  char*  B0     = w + 21 * MB + 256 * 1024;         // 21.25M
  float* xpart  = (float*)B0;                       // 8M  (alias B)
  float* Sb     = (float*)B0;                       // 16M (alias B)
  u16*   ybarb  = (u16*)B0;                         // 8M  (alias B)
  float* Hin    = (float*)(B0 + 16 * MB);           // 16M
  float* xzres  = (float*)(B0 + 32 * MB);           // 32M
  float* xc     = (float*)(B0 + 64 * MB);           // 16M
  float* xdbl   = (float*)(B0 + 80 * MB);           // 1M
  float* delta  = (float*)(B0 + 81 * MB);           // 16M
  u16*   W_outb = (u16*)(B0 + 97 * MB);             // 4M

  dim3 blk(256);
  // fused casts (x, W_in, W_dt, W_out, W_x-pad)
  cast_all_k<<<CG_WX / 256, blk, 0, stream>>>(x, W_in, W_dt, W_out, W_x,
                                              xb, W_inb, W_dtb, W_outb, W_xb);
  // 1) in_proj: xzres[2048][4096] = xb[2048][1024] @ W_in[4096][1024]^T
  gemm_bt<0, 1><<<dim3(32, 16), blk, 0, stream>>>(xb, W_inb, xzres, nullptr,
                                                  4096, 1024, 1024, 1024, 4096, 0);
  // 2) conv + silu on xz half
  conv_silu_k<<<(CB * CLEN * CDI) / 256, blk, 0, stream>>>(xzres, (const float4*)conv_w,
                                                           conv_b, xc, xcb);
  // 3) x_proj (split-K=8): xpart[z][2048][128] = xcb @ W_xb^T, then reduce
  gemm_bt<0, 8><<<dim3(1, 16, 8), blk, 0, stream>>>(xcb, W_xb, xpart, nullptr,
                                                    128, 2048, 2048, 2048, 128,
                                                    (size_t)CM * 128);
  xdbl_reduce_k<<<(CM * 128 / 4) / 256, blk, 0, stream>>>(xpart, xdbl, xdblb);
  // 4) dt_proj + softplus: delta[2048][2048] = softplus(dlt @ W_dt^T + b_dt)
  gemm_bt<2, 1><<<dim3(16, 16), blk, 0, stream>>>(xdblb, W_dtb, delta, b_dt,
                                                  2048, 64, 128, 64, 2048, 0);
  // 5) selective scan (3-phase chunked, 64 chunks of 16)
  scan_p1<<<dim3(8, NCHUNK, 2), blk, 0, stream>>>(delta, xc, xdbl, A_log, Pb, Sb);
  scan_p2<<<dim3(8, 16, 2), blk, 0, stream>>>(Pb, Sb, Hin);
  scan_p3<<<dim3(8, NCHUNK, 2), blk, 0, stream>>>(delta, xc, xdbl, A_log, Dvec, xzres,
                                                  Hin, ybarb);
  // 6) out_proj: out[2048][1024] = ybarb @ W_out^T
  gemm_bt<0, 1><<<dim3(8, 16), blk, 0, stream>>>(ybarb, W_outb, out, nullptr,
                                                 1024, 2048, 2048, 2048, 1024, 0);
}

// Round 4
// 254.102 us; speedup vs baseline: 1.3489x; 1.0244x over previous
//
#include <hip/hip_runtime.h>
#include <hip/hip_bf16.h>
#include <cmath>

#define DEV __device__ __forceinline__

typedef float  f32x4  __attribute__((ext_vector_type(4)));
typedef __bf16 bf16x8 __attribute__((ext_vector_type(8)));
using u16 = unsigned short;

constexpr int CB   = 2;     // batch
constexpr int CLEN = 1024;  // seq len
constexpr int CDM  = 1024;  // d_model
constexpr int CDI  = 2048;  // d_inner
constexpr int CM   = CB * CLEN;  // 2048 GEMM rows
constexpr int NCHUNK = 64;  // scan chunks
constexpr int CHL    = 16;  // chunk length

DEV u16 f2bf(float f) {
  unsigned u = __builtin_bit_cast(unsigned, f);
  unsigned r = (u + 0x7fffu + ((u >> 16) & 1u)) >> 16;  // RNE
  return (u16)r;
}
DEV float bf2f(u16 v) { return __builtin_bit_cast(float, ((unsigned)v) << 16); }

DEV ushort4 f4bf(float4 v) {
  ushort4 o;
  o.x = f2bf(v.x); o.y = f2bf(v.y); o.z = f2bf(v.z); o.w = f2bf(v.w);
  return o;
}

// ------------------------------------------------------------------
// one fused cast kernel: x, W_in, W_dt, W_out (plain) + W_x (pad 96->128 rows)
// ------------------------------------------------------------------
constexpr int CG_X   = 524288;                 // 2048*1024/4
constexpr int CG_WIN = CG_X   + 1048576;       // 4096*1024/4
constexpr int CG_WDT = CG_WIN + 32768;         // 2048*64/4
constexpr int CG_WO  = CG_WDT + 524288;        // 1024*2048/4
constexpr int CG_WX  = CG_WO  + 65536;         // 128*2048/4 (padded out)

__global__ void cast_all_k(const float* __restrict__ x, const float* __restrict__ W_in,
                           const float* __restrict__ W_dt, const float* __restrict__ W_out,
                           const float* __restrict__ W_x,
                           u16* __restrict__ xb, u16* __restrict__ W_inb,
                           u16* __restrict__ W_dtb, u16* __restrict__ W_outb,
                           u16* __restrict__ W_xb)
{
  int i = blockIdx.x * blockDim.x + threadIdx.x;
  if (i < CG_X) {
    reinterpret_cast<ushort4*>(xb)[i] = f4bf(reinterpret_cast<const float4*>(x)[i]);
  } else if (i < CG_WIN) {
    int j = i - CG_X;
    reinterpret_cast<ushort4*>(W_inb)[j] = f4bf(reinterpret_cast<const float4*>(W_in)[j]);
  } else if (i < CG_WDT) {
    int j = i - CG_WIN;
    reinterpret_cast<ushort4*>(W_dtb)[j] = f4bf(reinterpret_cast<const float4*>(W_dt)[j]);
  } else if (i < CG_WO) {
    int j = i - CG_WDT;
    reinterpret_cast<ushort4*>(W_outb)[j] = f4bf(reinterpret_cast<const float4*>(W_out)[j]);
  } else {
    int j = i - CG_WO;
    int base = j * 4, row = base >> 11, col = base & 2047;
    float4 v = make_float4(0.f, 0.f, 0.f, 0.f);
    if (row < 96) v = *reinterpret_cast<const float4*>(W_x + row * 2048 + col);
    reinterpret_cast<ushort4*>(W_xb)[j] = f4bf(v);
  }
}

// ------------------------------------------------------------------
// bf16 MFMA GEMM, NT layout: C[M][N] = A[M][K] * B[N][K]^T
// 128x128 tile, BK=32, 4 waves each computing 64x64 (4x4 MFMA tiles)
// EPI: 0 = fp32 store; 1 = bf16 store only; 3 = softplus(acc+bias)->bf16 only
// SPLITK>1: blockIdx.z picks a K-slice, partial fp32 to C + z*slice_stride
// ------------------------------------------------------------------
DEV void gload_lds16(const void* g, void* l) {
  __builtin_amdgcn_global_load_lds(
      (const __attribute__((address_space(1))) void*)g,
      (__attribute__((address_space(3))) void*)l, 16, 0, 0);
}

template <int EPI, int SPLITK>
__global__ __launch_bounds__(256, 2)
void gemm_bt(const u16* __restrict__ A, const u16* __restrict__ Bw,
             float* __restrict__ C, u16* __restrict__ Cb,
             const float* __restrict__ bias,
             int Nd, int Kd, int lda, int ldb, int ldc, size_t slice_stride)
{
  __shared__ u16 As[128 * 32];
  __shared__ u16 Bs[128 * 32];
  const int tid  = threadIdx.x;
  const int wave = tid >> 6;
  const int lane = tid & 63;
  const int wm = wave >> 1, wn = wave & 1;
  const int row0 = blockIdx.y * 128;
  const int col0 = blockIdx.x * 128;
  const int lr = lane >> 2;        // row within a 16-row staging chunk
  const int lc = (lane & 3) * 8;   // 8 bf16 = 16B per lane

  const int kper = Kd / SPLITK;
  const int kbeg = (SPLITK > 1) ? blockIdx.z * kper : 0;
  float* Cz = (SPLITK > 1) ? C + (size_t)blockIdx.z * slice_stride : C;

  f32x4 acc[4][4] = {};

  for (int k0 = kbeg; k0 < kbeg + kper; k0 += 32) {
#pragma unroll
    for (int j = 0; j < 2; ++j) {
      const int rb = j * 64 + wave * 16;   // 16 rows per issue per wave
      gload_lds16(A  + (size_t)(row0 + rb + lr) * lda + k0 + lc, As + rb * 32);
      gload_lds16(Bw + (size_t)(col0 + rb + lr) * ldb + k0 + lc, Bs + rb * 32);
    }
    __syncthreads();   // drains vmcnt for global_load_lds

    const int q  = lane >> 4;
    const int mr = lane & 15;
    bf16x8 af[4], bfr[4];
#pragma unroll
    for (int t = 0; t < 4; ++t) {
      af[t]  = *reinterpret_cast<const bf16x8*>(As + (wm * 64 + t * 16 + mr) * 32 + q * 8);
      bfr[t] = *reinterpret_cast<const bf16x8*>(Bs + (wn * 64 + t * 16 + mr) * 32 + q * 8);
    }
#pragma unroll
    for (int mt = 0; mt < 4; ++mt)
#pragma unroll
      for (int nt = 0; nt < 4; ++nt)
        acc[mt][nt] = __builtin_amdgcn_mfma_f32_16x16x32_bf16(af[mt], bfr[nt], acc[mt][nt], 0, 0, 0);
    __syncthreads();
  }

  const int q  = lane >> 4;
  const int cn = lane & 15;
#pragma unroll
  for (int mt = 0; mt < 4; ++mt)
#pragma unroll
    for (int nt = 0; nt < 4; ++nt)
#pragma unroll
      for (int r = 0; r < 4; ++r) {
        const int row = row0 + wm * 64 + mt * 16 + q * 4 + r;
        const int col = col0 + wn * 64 + nt * 16 + cn;
        float v = acc[mt][nt][r];
        if (EPI == 3) {
          v += bias[col];
          v = (v > 15.f) ? v : log1pf(__expf(v));   // softplus
        }
        if (EPI == 0) Cz[(size_t)row * ldc + col] = v;
        else          Cb[(size_t)row * ldc + col] = f2bf(v);
      }
}

// reduce 8 split-K partials of x_proj -> fp32 xdbl + bf16 xdblb
__global__ void xdbl_reduce_k(const float* __restrict__ part,
                              float* __restrict__ xdbl, u16* __restrict__ xdblb)
{
  int i = blockIdx.x * blockDim.x + threadIdx.x;   // over 2048*128/4 groups
  float4 s = reinterpret_cast<const float4*>(part)[i];
#pragma unroll
  for (int z = 1; z < 8; ++z) {
    float4 p = reinterpret_cast<const float4*>(part + (size_t)z * CM * 128)[i];
    s.x += p.x; s.y += p.y; s.z += p.z; s.w += p.w;
  }
  reinterpret_cast<float4*>(xdbl)[i] = s;
  reinterpret_cast<ushort4*>(xdblb)[i] = f4bf(s);
}

// reduce 4 split-K partials of out_proj -> fp32 out
__global__ void out_reduce_k(const float* __restrict__ part, float* __restrict__ out)
{
  int i = blockIdx.x * blockDim.x + threadIdx.x;   // over 2048*1024/4 groups
  float4 s = reinterpret_cast<const float4*>(part)[i];
#pragma unroll
  for (int z = 1; z < 4; ++z) {
    float4 p = reinterpret_cast<const float4*>(part + (size_t)z * CM * CDM)[i];
    s.x += p.x; s.y += p.y; s.z += p.z; s.w += p.w;
  }
  reinterpret_cast<float4*>(out)[i] = s;
}

// ------------------------------------------------------------------
// causal depthwise conv (k=4) + SiLU on xz half -> xcb (bf16);
// silu(res) on res half -> rsb (bf16)
// ------------------------------------------------------------------
__global__ void conv_silu_k(const u16* __restrict__ xzb, const float4* __restrict__ cw4,
                            const float* __restrict__ cb,
                            u16* __restrict__ xcb, u16* __restrict__ rsb)
{
  int idx = blockIdx.x * blockDim.x + threadIdx.x;  // over CB*CLEN*CDI
  int d   = idx & (CDI - 1);
  int row = idx >> 11;            // b*L + l
  int l   = row & (CLEN - 1);
  float4 wv = cw4[d];
  const float* wp = (const float*)&wv;
  float acc = cb[d];
#pragma unroll
  for (int i = 0; i < 4; ++i) {
    int ls = l - 3 + i;
    float v = (ls >= 0) ? bf2f(xzb[(size_t)(row - l + ls) * 4096 + d]) : 0.f;
    acc += v * wp[i];
  }
  float s = acc / (1.f + __expf(-acc));   // silu
  xcb[idx] = f2bf(s);
  float r = bf2f(xzb[(size_t)row * 4096 + CDI + d]);
  rsb[idx] = f2bf(r / (1.f + __expf(-r)));
}

// ------------------------------------------------------------------
// chunked selective scan (3 phases); P/S/Hin layout [b][chunk][n][d]
// ------------------------------------------------------------------
__global__ __launch_bounds__(256)
void scan_p1(const u16* __restrict__ delta_b, const u16* __restrict__ xcb,
             const float* __restrict__ xdbl, const float* __restrict__ A_log,
             float* __restrict__ P, float* __restrict__ S)
{
  __shared__ float sB[CHL * 16];
  const int t = threadIdx.x;
  const int d = blockIdx.x * 256 + t;
  const int c = blockIdx.y, b = blockIdx.z;

  if (t < CHL * 16) {
    int ll = t >> 4, n = t & 15;
    sB[t] = xdbl[(size_t)(b * CLEN + c * CHL + ll) * 128 + 64 + n];
  }
  __syncthreads();

  float An[16], Pv[16], Sv[16];
#pragma unroll
  for (int n = 0; n < 16; ++n) {
    An[n] = -__expf(A_log[d * 16 + n]);
    Pv[n] = 1.f; Sv[n] = 0.f;
  }
  const size_t rbase = (size_t)(b * CLEN + c * CHL) * CDI + d;
  for (int ll = 0; ll < CHL; ++ll) {
    float dl = bf2f(delta_b[rbase + (size_t)ll * CDI]);
    float u  = bf2f(xcb[rbase + (size_t)ll * CDI]);
    float du = dl * u;
#pragma unroll
    for (int n = 0; n < 16; ++n) {
      float a = __expf(dl * An[n]);
      Pv[n] *= a;
      Sv[n] = a * Sv[n] + du * sB[ll * 16 + n];
    }
  }
  const size_t o = (size_t)((b * NCHUNK + c) * 16) * CDI + d;
#pragma unroll
  for (int n = 0; n < 16; ++n) {
    P[o + (size_t)n * CDI] = Pv[n];
    S[o + (size_t)n * CDI] = Sv[n];
  }
}

__global__ void scan_p2(const float* __restrict__ P, const float* __restrict__ S,
                        float* __restrict__ Hin)
{
  const int t = threadIdx.x;
  const int d = blockIdx.x * 256 + t;
  const int n = blockIdx.y, b = blockIdx.z;
  float h = 0.f;
#pragma unroll 8
  for (int c = 0; c < NCHUNK; ++c) {
    size_t o = (size_t)((b * NCHUNK + c) * 16 + n) * CDI + d;
    Hin[o] = h;
    h = P[o] * h + S[o];
  }
}

__global__ __launch_bounds__(256)
void scan_p3(const u16* __restrict__ delta_b, const u16* __restrict__ xcb,
             const float* __restrict__ xdbl, const float* __restrict__ A_log,
             const float* __restrict__ Dvec, const u16* __restrict__ rsb,
             const float* __restrict__ Hin, u16* __restrict__ ybarb)
{
  __shared__ float sB[CHL * 16];
  __shared__ float sC[CHL * 16];
  const int t = threadIdx.x;
  const int d = blockIdx.x * 256 + t;
  const int c = blockIdx.y, b = blockIdx.z;

  if (t < CHL * 16) {
    int ll = t >> 4, n = t & 15;
    size_t ro = (size_t)(b * CLEN + c * CHL + ll) * 128;
    sB[t] = xdbl[ro + 64 + n];
    sC[t] = xdbl[ro + 80 + n];
  }
  __syncthreads();

  float An[16], h[16];
  const size_t ho = (size_t)((b * NCHUNK + c) * 16) * CDI + d;
#pragma unroll
  for (int n = 0; n < 16; ++n) {
    An[n] = -__expf(A_log[d * 16 + n]);
    h[n]  = Hin[ho + (size_t)n * CDI];
  }
  const float Dd = Dvec[d];
  const size_t rbase = (size_t)(b * CLEN + c * CHL);
  for (int ll = 0; ll < CHL; ++ll) {
    size_t e = (rbase + ll) * CDI + d;
    float dl = bf2f(delta_b[e]);
    float u  = bf2f(xcb[e]);
    float du = dl * u;
    float y  = 0.f;
#pragma unroll
    for (int n = 0; n < 16; ++n) {
      float a = __expf(dl * An[n]);
      h[n] = a * h[n] + du * sB[ll * 16 + n];
      y += h[n] * sC[ll * 16 + n];
    }
    y += u * Dd;
    ybarb[e] = f2bf(y * bf2f(rsb[e]));
  }
}

// ------------------------------------------------------------------
extern "C" void kernel_launch(void* const* d_in, const int* in_sizes, int n_in,
                              void* d_out, int out_size, void* d_ws, size_t ws_size,
                              hipStream_t stream)
{
  (void)in_sizes; (void)n_in; (void)out_size; (void)ws_size;
  const float* x      = (const float*)d_in[0];
  const float* W_in   = (const float*)d_in[1];
  const float* conv_w = (const float*)d_in[2];
  const float* conv_b = (const float*)d_in[3];
  const float* W_x    = (const float*)d_in[4];
  const float* W_dt   = (const float*)d_in[5];
  const float* b_dt   = (const float*)d_in[6];
  const float* A_log  = (const float*)d_in[7];
  const float* Dvec   = (const float*)d_in[8];
  const float* W_out  = (const float*)d_in[9];
  float* out = (float*)d_out;

  // -------- workspace layout (lifetime-aliased; total 122.25 MB) --------
  // [0,16)  xzres_b  (gemm1 -> conv)            ┐
  // [16,20) xb       (cast -> gemm1)            │ opart (32M, out gemm ->
  // [20,28) W_inb    (cast -> gemm1)            │ reduce) aliases [0,32)
  // [28,36) xpart    (x_proj -> reduce)         ┘ (xpart tail [32,36) free)
  // [36,52) P   (p1->p2)   [52,68) S (p1->p2)   [68,84) Hin (p2->p3)
  // [84,..) persistent: xcb(8M) rsb(8M!) xdbl(1M) xdblb(.5) W_xb(.5)
  //         W_dtb(.25) delta_b(8M) ybarb(8M) W_outb(4M)
  constexpr size_t MB = 1048576;
  char* w = (char*)d_ws;
  u16*   xzres_b = (u16*)(w + 0);                     // 16M
  u16*   xb      = (u16*)(w + 16 * MB);               // 4M
  u16*   W_inb   = (u16*)(w + 20 * MB);               // 8M
  float* xpart   = (float*)(w + 28 * MB);             // 8M
  float* opart   = (float*)(w + 0);                   // 32M (alias, last stage)
  float* Pb      = (float*)(w + 36 * MB);             // 16M
  float* Sb      = (float*)(w + 52 * MB);             // 16M
  float* Hin     = (float*)(w + 68 * MB);             // 16M
  u16*   xcb     = (u16*)(w + 84 * MB);               // 8M
  u16*   rsb     = (u16*)(w + 92 * MB);               // 8M (2*1024*2048 bf16)
  float* xdbl    = (float*)(w + 100 * MB);            // 1M
  u16*   xdblb   = (u16*)(w + 101 * MB);              // 0.5M
  u16*   W_xb    = (u16*)(w + 101 * MB + 512 * 1024); // 0.5M
  u16*   W_dtb   = (u16*)(w + 102 * MB);              // 0.25M
  u16*   delta_b = (u16*)(w + 102 * MB + 256 * 1024); // 8M
  u16*   ybarb   = (u16*)(w + 110 * MB + 256 * 1024); // 8M
  u16*   W_outb  = (u16*)(w + 118 * MB + 256 * 1024); // 4M -> 122.25M total

  dim3 blk(256);
  // fused casts (x, W_in, W_dt, W_out, W_x-pad)
  cast_all_k<<<CG_WX / 256, blk, 0, stream>>>(x, W_in, W_dt, W_out, W_x,
                                              xb, W_inb, W_dtb, W_outb, W_xb);
  // 1) in_proj (bf16 out): xzres_b[2048][4096] = xb @ W_in^T
  gemm_bt<1, 1><<<dim3(32, 16), blk, 0, stream>>>(xb, W_inb, nullptr, xzres_b, nullptr,
                                                  4096, 1024, 1024, 1024, 4096, 0);
  // 2) conv + silu -> xcb; silu(res) -> rsb
  conv_silu_k<<<(CB * CLEN * CDI) / 256, blk, 0, stream>>>(xzres_b, (const float4*)conv_w,
                                                           conv_b, xcb, rsb);
  // 3) x_proj (split-K=8): xpart[z][2048][128] = xcb @ W_xb^T, then reduce
  gemm_bt<0, 8><<<dim3(1, 16, 8), blk, 0, stream>>>(xcb, W_xb, xpart, nullptr, nullptr,
                                                    128, 2048, 2048, 2048, 128,
                                                    (size_t)CM * 128);
  xdbl_reduce_k<<<(CM * 128 / 4) / 256, blk, 0, stream>>>(xpart, xdbl, xdblb);
  // 4) dt_proj + softplus -> bf16 delta
  gemm_bt<3, 1><<<dim3(16, 16), blk, 0, stream>>>(xdblb, W_dtb, nullptr, delta_b, b_dt,
                                                  2048, 64, 128, 64, 2048, 0);
  // 5) selective scan (3-phase chunked, 64 chunks of 16)
  scan_p1<<<dim3(8, NCHUNK, 2), blk, 0, stream>>>(delta_b, xcb, xdbl, A_log, Pb, Sb);
  scan_p2<<<dim3(8, 16, 2), blk, 0, stream>>>(Pb, Sb, Hin);
  scan_p3<<<dim3(8, NCHUNK, 2), blk, 0, stream>>>(delta_b, xcb, xdbl, A_log, Dvec, rsb,
                                                  Hin, ybarb);
  // 6) out_proj (split-K=4): opart[z][2048][1024] = ybarb @ W_out^T, then reduce
  gemm_bt<0, 4><<<dim3(8, 16, 4), blk, 0, stream>>>(ybarb, W_outb, opart, nullptr, nullptr,
                                                    1024, 2048, 2048, 2048, 1024,
                                                    (size_t)CM * CDM);
  out_reduce_k<<<(CM * CDM / 4) / 256, blk, 0, stream>>>(opart, out);
}